// Round 6
// baseline (128.483 us; speedup 1.0000x reference)
//
#include <hip/hip_runtime.h>

#define BATCH 4096
#define DIM   128
#define NT    32   // 4096 / 128 tiles per dimension
// TEMP = 0.25 -> 1/T = 4; 4*log2(e):
#define EXP_SCALE 5.770780163555854f

typedef __bf16 bf16_t;
typedef __bf16 bf16x8 __attribute__((ext_vector_type(8)));
typedef float  f32x4  __attribute__((ext_vector_type(4)));

// ---------------------------------------------------------------------------
// Kernel A: per row k, normalize emb_i[k] and emb_j[k] (fp32 math), write
// bf16 z_i, z_j to workspace, pos[k] = cos-sim in fp32. One wave per row.
// Blocks 0..7 zero exactly the rowDenom/colDenom region (8 x 256 x 4 floats
// = 8192 floats = 32 KB); block 8 zeroes the completion counter used by
// kernel B's fused finalize. (Workspace is poisoned before every run, so
// the counter MUST be zeroed here.)
// ---------------------------------------------------------------------------
__global__ __launch_bounds__(256) void normalize_kernel(
    const float* __restrict__ emb_i, const float* __restrict__ emb_j,
    bf16_t* __restrict__ zi, bf16_t* __restrict__ zj, float* __restrict__ pos,
    float* __restrict__ denoms /* rowDenom(4096) ++ colDenom(4096) */,
    unsigned* __restrict__ counter)
{
    if (blockIdx.x < 8) {
        int idx = (blockIdx.x * 256 + threadIdx.x) * 4;
        *(float4*)&denoms[idx] = make_float4(0.f, 0.f, 0.f, 0.f);
    }
    if (blockIdx.x == 8 && threadIdx.x == 0) *counter = 0u;

    int wave = threadIdx.x >> 6;
    int lane = threadIdx.x & 63;
    int k = blockIdx.x * 4 + wave;

    const float2* ei = (const float2*)(emb_i + (size_t)k * DIM);
    const float2* ej = (const float2*)(emb_j + (size_t)k * DIM);
    float2 a = ei[lane];
    float2 b = ej[lane];

    float sii = a.x * a.x + a.y * a.y;
    float sjj = b.x * b.x + b.y * b.y;
    float sij = a.x * b.x + a.y * b.y;
#pragma unroll
    for (int m = 1; m < 64; m <<= 1) {
        sii += __shfl_xor(sii, m);
        sjj += __shfl_xor(sjj, m);
        sij += __shfl_xor(sij, m);
    }
    float inv_i = 1.0f / fmaxf(sqrtf(sii), 1e-12f);
    float inv_j = 1.0f / fmaxf(sqrtf(sjj), 1e-12f);

    struct bf16_2 { bf16_t x, y; };
    bf16_2 pi, pj;
    pi.x = (bf16_t)(a.x * inv_i);  pi.y = (bf16_t)(a.y * inv_i);
    pj.x = (bf16_t)(b.x * inv_j);  pj.y = (bf16_t)(b.y * inv_j);
    ((bf16_2*)(zi + (size_t)k * DIM))[lane] = pi;
    ((bf16_2*)(zj + (size_t)k * DIM))[lane] = pj;

    if (lane == 0) pos[k] = sij * inv_i * inv_j;
}

// ---------------------------------------------------------------------------
// Kernel B: 128x128 tile of S = Zi * Zj^T per block (grid 32x32) --
// byte-identical GEMM/epilogue to the proven 74.6 us baseline (no XCD
// swizzle: zi/zj = 2 MB replicate into every XCD L2, measured null) --
// PLUS fused finalize: after a block's denominator atomics drain
// (__syncthreads implies s_waitcnt vmcnt(0) on gfx950) and a device fence,
// thread 0 takes a ticket; the block drawing ticket 1023 knows all 1024
// blocks' device-scope atomics have completed, so it performs kernel C's
// 48 KB read + log + reduce and writes the loss. Dispatches: 3 -> 2.
// ---------------------------------------------------------------------------
__global__ __launch_bounds__(256) void gemm_exp_kernel(
    const bf16_t* __restrict__ zi, const bf16_t* __restrict__ zj,
    float* __restrict__ rowDenom, float* __restrict__ colDenom,
    const float* __restrict__ pos, unsigned* __restrict__ counter,
    float* __restrict__ out)
{
    __shared__ __align__(16) bf16_t zi_s[128][136];
    __shared__ __align__(16) bf16_t zj_s[128][136];
    __shared__ float colRed[4][128];
    __shared__ unsigned ticket_s;

    const int tid = threadIdx.x;
    const int ti = blockIdx.x, tj = blockIdx.y;

    // Stage 128x128 bf16 of each matrix: 2048 16B-chunks / matrix, 8 iters.
#pragma unroll
    for (int it = 0; it < 8; ++it) {
        int c = it * 256 + tid;
        int row = c >> 4;          // 16 chunks per row
        int col = (c & 15) << 3;   // 8 bf16 per chunk
        *(uint4*)&zi_s[row][col] =
            *(const uint4*)(zi + ((size_t)(ti * 128 + row)) * DIM + col);
        *(uint4*)&zj_s[row][col] =
            *(const uint4*)(zj + ((size_t)(tj * 128 + row)) * DIM + col);
    }
    __syncthreads();

    const int wave = tid >> 6;
    const int lane = tid & 63;
    const int l15  = lane & 15;
    const int quad = lane >> 4;

    const f32x4 vzero = {0.f, 0.f, 0.f, 0.f};
    f32x4 acc[2][8];
#pragma unroll
    for (int rt = 0; rt < 2; ++rt)
#pragma unroll
        for (int ct = 0; ct < 8; ++ct) acc[rt][ct] = vzero;

#pragma unroll
    for (int ks = 0; ks < 4; ++ks) {
        int k0 = ks * 32 + quad * 8;
        bf16x8 afrag[2], bfrag[8];
#pragma unroll
        for (int rt = 0; rt < 2; ++rt)
            afrag[rt] = *(const bf16x8*)&zi_s[(wave * 2 + rt) * 16 + l15][k0];
#pragma unroll
        for (int ct = 0; ct < 8; ++ct)
            bfrag[ct] = *(const bf16x8*)&zj_s[ct * 16 + l15][k0];
#pragma unroll
        for (int rt = 0; rt < 2; ++rt)
#pragma unroll
            for (int ct = 0; ct < 8; ++ct)
                acc[rt][ct] = __builtin_amdgcn_mfma_f32_16x16x32_bf16(
                    afrag[rt], bfrag[ct], acc[rt][ct], 0, 0, 0);
    }

    // Epilogue: exp and partial sums.
    float rowPart[2][4] = {{0.f, 0.f, 0.f, 0.f}, {0.f, 0.f, 0.f, 0.f}};
    float colPart[8]    = {0.f, 0.f, 0.f, 0.f, 0.f, 0.f, 0.f, 0.f};
#pragma unroll
    for (int rt = 0; rt < 2; ++rt)
#pragma unroll
        for (int ct = 0; ct < 8; ++ct)
#pragma unroll
            for (int r = 0; r < 4; ++r) {
                float e = exp2f(acc[rt][ct][r] * EXP_SCALE);
                rowPart[rt][r] += e;   // row = (wave*2+rt)*16 + quad*4 + r
                colPart[ct]    += e;   // col = ct*16 + l15
            }

    // Row sums: each wave's rows see all 128 tile columns; 16-lane shfl
    // reduce completes them. One atomic per row per block.
#pragma unroll
    for (int rt = 0; rt < 2; ++rt)
#pragma unroll
        for (int r = 0; r < 4; ++r) {
            float v = rowPart[rt][r];
            v += __shfl_xor(v, 1);
            v += __shfl_xor(v, 2);
            v += __shfl_xor(v, 4);
            v += __shfl_xor(v, 8);
            if (l15 == 0) {
                int grow = ti * 128 + (wave * 2 + rt) * 16 + quad * 4 + r;
                atomicAdd(&rowDenom[grow], v);
            }
        }

    // Col sums: quad shfl-reduce, then cross-wave LDS reduce, then one
    // coalesced atomic per column per block.
#pragma unroll
    for (int ct = 0; ct < 8; ++ct) {
        float v = colPart[ct];
        v += __shfl_xor(v, 16);
        v += __shfl_xor(v, 32);
        if (quad == 0) colRed[wave][ct * 16 + l15] = v;
    }
    __syncthreads();
    if (tid < 128) {
        float s = colRed[0][tid] + colRed[1][tid] + colRed[2][tid] + colRed[3][tid];
        atomicAdd(&colDenom[tj * 128 + tid], s);
    }

    // ---- Fused finalize (last block only) ----
    // Barrier drains every thread's atomics (compiler emits s_waitcnt
    // vmcnt(0) before s_barrier); fence + device-scope ticket then gives
    // the classic last-block-done guarantee across XCDs.
    __syncthreads();
    __threadfence();
    if (tid == 0) ticket_s = atomicAdd(counter, 1u);
    __syncthreads();
    if (ticket_s == (NT * NT - 1)) {
        float acc2 = 0.f;
#pragma unroll
        for (int it = 0; it < 16; ++it) {
            int k = it * 256 + tid;
            acc2 += logf(rowDenom[k]) + logf(colDenom[k]) - 8.0f * pos[k];
        }
#pragma unroll
        for (int m = 1; m < 64; m <<= 1) acc2 += __shfl_xor(acc2, m);
        if ((tid & 63) == 0) colRed[0][tid >> 6] = acc2;
        __syncthreads();
        if (tid == 0)
            out[0] = (colRed[0][0] + colRed[0][1] + colRed[0][2] + colRed[0][3]) *
                     (1.0f / (2.0f * BATCH));
    }
}

extern "C" void kernel_launch(void* const* d_in, const int* in_sizes, int n_in,
                              void* d_out, int out_size, void* d_ws, size_t ws_size,
                              hipStream_t stream) {
    const float* emb_i = (const float*)d_in[0];
    const float* emb_j = (const float*)d_in[1];
    float* out = (float*)d_out;

    char* ws = (char*)d_ws;
    bf16_t*   zi      = (bf16_t*)(ws);                 // 1 MB
    bf16_t*   zj      = (bf16_t*)(ws + (1u << 20));    // 1 MB
    float*    denoms  = (float*)(ws + (2u << 20));     // 32 KB (row ++ col)
    float*    pos     = denoms + 2 * BATCH;            // 16 KB
    unsigned* counter = (unsigned*)(pos + BATCH);      // 4 B

    normalize_kernel<<<BATCH / 4, 256, 0, stream>>>(emb_i, emb_j, zi, zj, pos,
                                                    denoms, counter);
    gemm_exp_kernel<<<dim3(NT, NT), 256, 0, stream>>>(zi, zj, denoms,
                                                      denoms + BATCH, pos,
                                                      counter, out);
}

// Round 7
// 79.695 us; speedup vs baseline: 1.6122x; 1.6122x over previous
//
#include <hip/hip_runtime.h>

#define BATCH 4096
#define DIM   128
#define NT    32   // 4096 / 128 tiles per dimension
// TEMP = 0.25 -> 1/T = 4; 4*log2(e):
#define EXP_SCALE 5.770780163555854f

typedef __bf16 bf16_t;
typedef __bf16 bf16x8 __attribute__((ext_vector_type(8)));
typedef float  f32x4  __attribute__((ext_vector_type(4)));

// ---------------------------------------------------------------------------
// Kernel A: per row k, normalize emb_i[k] and emb_j[k] (fp32 math), write
// bf16 z_i, z_j to workspace, pos[k] = cos-sim in fp32. One wave per row.
// Blocks 0..7 zero exactly the rowDenom/colDenom region (8 x 256 x 4 floats
// = 8192 floats = 32 KB) -- race-free (no overshoot into pos[]).
// ---------------------------------------------------------------------------
__global__ __launch_bounds__(256) void normalize_kernel(
    const float* __restrict__ emb_i, const float* __restrict__ emb_j,
    bf16_t* __restrict__ zi, bf16_t* __restrict__ zj, float* __restrict__ pos,
    float* __restrict__ denoms /* rowDenom(4096) ++ colDenom(4096) */)
{
    if (blockIdx.x < 8) {
        int idx = (blockIdx.x * 256 + threadIdx.x) * 4;
        *(float4*)&denoms[idx] = make_float4(0.f, 0.f, 0.f, 0.f);
    }

    int wave = threadIdx.x >> 6;
    int lane = threadIdx.x & 63;
    int k = blockIdx.x * 4 + wave;

    const float2* ei = (const float2*)(emb_i + (size_t)k * DIM);
    const float2* ej = (const float2*)(emb_j + (size_t)k * DIM);
    float2 a = ei[lane];
    float2 b = ej[lane];

    float sii = a.x * a.x + a.y * a.y;
    float sjj = b.x * b.x + b.y * b.y;
    float sij = a.x * b.x + a.y * b.y;
#pragma unroll
    for (int m = 1; m < 64; m <<= 1) {
        sii += __shfl_xor(sii, m);
        sjj += __shfl_xor(sjj, m);
        sij += __shfl_xor(sij, m);
    }
    float inv_i = 1.0f / fmaxf(sqrtf(sii), 1e-12f);
    float inv_j = 1.0f / fmaxf(sqrtf(sjj), 1e-12f);

    struct bf16_2 { bf16_t x, y; };
    bf16_2 pi, pj;
    pi.x = (bf16_t)(a.x * inv_i);  pi.y = (bf16_t)(a.y * inv_i);
    pj.x = (bf16_t)(b.x * inv_j);  pj.y = (bf16_t)(b.y * inv_j);
    ((bf16_2*)(zi + (size_t)k * DIM))[lane] = pi;
    ((bf16_2*)(zj + (size_t)k * DIM))[lane] = pj;

    if (lane == 0) pos[k] = sij * inv_i * inv_j;
}

// ---------------------------------------------------------------------------
// Kernel B: 128x128 tile of S = Zi * Zj^T per block (grid 32x32).
// Round-6 profile (VGPR=92, LDS=72KB -> 2 blocks/CU, Occupancy 18.7%,
// all pipes <10%) says K2 is LATENCY/OCCUPANCY-bound. Change vs the
// proven 74.6us baseline: stage K in two 64-wide halves reusing ONE
// buffer per matrix -> LDS 72 KB -> 38 KB -> 4 blocks/CU, so the serial
// stage/sync/compute/epilogue phases of co-resident blocks overlap.
// Pad 64->72 cols: row stride 144 B = 36 banks == 4 mod 32 -> identical
// free 2-way bank pattern as the old 136-pad; 16B alignment preserved.
// No __threadfence anywhere (round-6: device fences flush L2 -> 76us).
// Epilogue unchanged: exp2, wave shfl-reduce, atomics to denoms.
// ---------------------------------------------------------------------------
__global__ __launch_bounds__(256) void gemm_exp_kernel(
    const bf16_t* __restrict__ zi, const bf16_t* __restrict__ zj,
    float* __restrict__ rowDenom, float* __restrict__ colDenom)
{
    __shared__ __align__(16) bf16_t zi_s[128][72];
    __shared__ __align__(16) bf16_t zj_s[128][72];
    __shared__ float colRed[4][128];

    const int tid = threadIdx.x;
    const int ti = blockIdx.x, tj = blockIdx.y;

    const int wave = tid >> 6;
    const int lane = tid & 63;
    const int l15  = lane & 15;
    const int quad = lane >> 4;

    const f32x4 vzero = {0.f, 0.f, 0.f, 0.f};
    f32x4 acc[2][8];
#pragma unroll
    for (int rt = 0; rt < 2; ++rt)
#pragma unroll
        for (int ct = 0; ct < 8; ++ct) acc[rt][ct] = vzero;

#pragma unroll
    for (int h = 0; h < 2; ++h) {
        if (h) __syncthreads();   // previous half's reads complete

        // Stage 64-wide K-half of both matrices: per matrix 128 rows x
        // 128 B = 1024 16B-chunks, 4 iters of 256 threads.
#pragma unroll
        for (int it = 0; it < 4; ++it) {
            int c = it * 256 + tid;
            int row = c >> 3;          // 8 chunks per row
            int col = (c & 7) << 3;    // 8 bf16 per chunk
            *(uint4*)&zi_s[row][col] =
                *(const uint4*)(zi + ((size_t)(ti * 128 + row)) * DIM + h * 64 + col);
            *(uint4*)&zj_s[row][col] =
                *(const uint4*)(zj + ((size_t)(tj * 128 + row)) * DIM + h * 64 + col);
        }
        __syncthreads();

#pragma unroll
        for (int ks = 0; ks < 2; ++ks) {
            int k0 = ks * 32 + quad * 8;
            bf16x8 afrag[2], bfrag[8];
#pragma unroll
            for (int rt = 0; rt < 2; ++rt)
                afrag[rt] = *(const bf16x8*)&zi_s[(wave * 2 + rt) * 16 + l15][k0];
#pragma unroll
            for (int ct = 0; ct < 8; ++ct)
                bfrag[ct] = *(const bf16x8*)&zj_s[ct * 16 + l15][k0];
#pragma unroll
            for (int rt = 0; rt < 2; ++rt)
#pragma unroll
                for (int ct = 0; ct < 8; ++ct)
                    acc[rt][ct] = __builtin_amdgcn_mfma_f32_16x16x32_bf16(
                        afrag[rt], bfrag[ct], acc[rt][ct], 0, 0, 0);
        }
    }

    // Epilogue: exp and partial sums.
    float rowPart[2][4] = {{0.f, 0.f, 0.f, 0.f}, {0.f, 0.f, 0.f, 0.f}};
    float colPart[8]    = {0.f, 0.f, 0.f, 0.f, 0.f, 0.f, 0.f, 0.f};
#pragma unroll
    for (int rt = 0; rt < 2; ++rt)
#pragma unroll
        for (int ct = 0; ct < 8; ++ct)
#pragma unroll
            for (int r = 0; r < 4; ++r) {
                float e = exp2f(acc[rt][ct][r] * EXP_SCALE);
                rowPart[rt][r] += e;   // row = (wave*2+rt)*16 + quad*4 + r
                colPart[ct]    += e;   // col = ct*16 + l15
            }

    // Row sums: each wave's rows see all 128 tile columns; 16-lane shfl
    // reduce completes them. One atomic per row per block.
#pragma unroll
    for (int rt = 0; rt < 2; ++rt)
#pragma unroll
        for (int r = 0; r < 4; ++r) {
            float v = rowPart[rt][r];
            v += __shfl_xor(v, 1);
            v += __shfl_xor(v, 2);
            v += __shfl_xor(v, 4);
            v += __shfl_xor(v, 8);
            if (l15 == 0) {
                int grow = ti * 128 + (wave * 2 + rt) * 16 + quad * 4 + r;
                atomicAdd(&rowDenom[grow], v);
            }
        }

    // Col sums: quad shfl-reduce, then cross-wave LDS reduce, then one
    // coalesced atomic per column per block.
#pragma unroll
    for (int ct = 0; ct < 8; ++ct) {
        float v = colPart[ct];
        v += __shfl_xor(v, 16);
        v += __shfl_xor(v, 32);
        if (quad == 0) colRed[wave][ct * 16 + l15] = v;
    }
    __syncthreads();
    if (tid < 128) {
        float s = colRed[0][tid] + colRed[1][tid] + colRed[2][tid] + colRed[3][tid];
        atomicAdd(&colDenom[tj * 128 + tid], s);
    }
}

// ---------------------------------------------------------------------------
// Kernel C: loss = (1/2B) * sum_k [log rowDenom_k + log colDenom_k - 8*pos_k]
// Only 48 KB of reads -> single block is fine.
// ---------------------------------------------------------------------------
__global__ __launch_bounds__(256) void finalize_kernel(
    const float* __restrict__ denoms, const float* __restrict__ pos,
    float* __restrict__ out)
{
    const float* rowDenom = denoms;
    const float* colDenom = denoms + BATCH;
    int tid = threadIdx.x;
    float acc = 0.f;
#pragma unroll
    for (int it = 0; it < 16; ++it) {
        int k = it * 256 + tid;
        acc += logf(rowDenom[k]) + logf(colDenom[k]) - 8.0f * pos[k];
    }
#pragma unroll
    for (int m = 1; m < 64; m <<= 1) acc += __shfl_xor(acc, m);
    __shared__ float red[4];
    if ((tid & 63) == 0) red[tid >> 6] = acc;
    __syncthreads();
    if (tid == 0)
        out[0] = (red[0] + red[1] + red[2] + red[3]) * (1.0f / (2.0f * BATCH));
}

extern "C" void kernel_launch(void* const* d_in, const int* in_sizes, int n_in,
                              void* d_out, int out_size, void* d_ws, size_t ws_size,
                              hipStream_t stream) {
    const float* emb_i = (const float*)d_in[0];
    const float* emb_j = (const float*)d_in[1];
    float* out = (float*)d_out;

    char* ws = (char*)d_ws;
    bf16_t* zi     = (bf16_t*)(ws);                 // 1 MB
    bf16_t* zj     = (bf16_t*)(ws + (1u << 20));    // 1 MB
    float*  denoms = (float*)(ws + (2u << 20));     // 32 KB (row ++ col)
    float*  pos    = denoms + 2 * BATCH;            // 16 KB

    normalize_kernel<<<BATCH / 4, 256, 0, stream>>>(emb_i, emb_j, zi, zj, pos, denoms);
    gemm_exp_kernel<<<dim3(NT, NT), 256, 0, stream>>>(zi, zj, denoms, denoms + BATCH);
    finalize_kernel<<<1, 256, 0, stream>>>(denoms, pos, out);
}

// Round 8
// 74.376 us; speedup vs baseline: 1.7275x; 1.0715x over previous
//
#include <hip/hip_runtime.h>

#define BATCH 4096
#define DIM   128
#define NT    32   // 4096 / 128 tiles per dimension
// TEMP = 0.25 -> 1/T = 4; 4*log2(e):
#define EXP_SCALE 5.770780163555854f

typedef __bf16 bf16_t;
typedef __bf16 bf16x8 __attribute__((ext_vector_type(8)));
typedef float  f32x4  __attribute__((ext_vector_type(4)));

// ---------------------------------------------------------------------------
// Kernel A: per row k, normalize emb_i[k] and emb_j[k] (fp32 math), write
// bf16 z_i, z_j to workspace, pos[k] = cos-sim in fp32. One wave per row.
// Blocks 0..7 zero exactly the rowDenom/colDenom region (8 x 256 x 4 floats
// = 8192 floats = 32 KB) -- race-free (no overshoot into pos[]).
// ---------------------------------------------------------------------------
__global__ __launch_bounds__(256) void normalize_kernel(
    const float* __restrict__ emb_i, const float* __restrict__ emb_j,
    bf16_t* __restrict__ zi, bf16_t* __restrict__ zj, float* __restrict__ pos,
    float* __restrict__ denoms /* rowDenom(4096) ++ colDenom(4096) */)
{
    if (blockIdx.x < 8) {
        int idx = (blockIdx.x * 256 + threadIdx.x) * 4;
        *(float4*)&denoms[idx] = make_float4(0.f, 0.f, 0.f, 0.f);
    }

    int wave = threadIdx.x >> 6;
    int lane = threadIdx.x & 63;
    int k = blockIdx.x * 4 + wave;

    const float2* ei = (const float2*)(emb_i + (size_t)k * DIM);
    const float2* ej = (const float2*)(emb_j + (size_t)k * DIM);
    float2 a = ei[lane];
    float2 b = ej[lane];

    float sii = a.x * a.x + a.y * a.y;
    float sjj = b.x * b.x + b.y * b.y;
    float sij = a.x * b.x + a.y * b.y;
#pragma unroll
    for (int m = 1; m < 64; m <<= 1) {
        sii += __shfl_xor(sii, m);
        sjj += __shfl_xor(sjj, m);
        sij += __shfl_xor(sij, m);
    }
    float inv_i = 1.0f / fmaxf(sqrtf(sii), 1e-12f);
    float inv_j = 1.0f / fmaxf(sqrtf(sjj), 1e-12f);

    struct bf16_2 { bf16_t x, y; };
    bf16_2 pi, pj;
    pi.x = (bf16_t)(a.x * inv_i);  pi.y = (bf16_t)(a.y * inv_i);
    pj.x = (bf16_t)(b.x * inv_j);  pj.y = (bf16_t)(b.y * inv_j);
    ((bf16_2*)(zi + (size_t)k * DIM))[lane] = pi;
    ((bf16_2*)(zj + (size_t)k * DIM))[lane] = pj;

    if (lane == 0) pos[k] = sij * inv_i * inv_j;
}

// ---------------------------------------------------------------------------
// Kernel B: 128x128 tile of S = Zi * Zj^T per block (grid 32x32).
// Byte-identical to the proven 74.6us baseline body: single-stage 72KB LDS
// (R7 showed split-staging/higher-occupancy is WORSE: staging wants all 16
// loads/thread in flight at once), no XCD swizzle (R4: null, zi/zj L2-fit),
// no fences (R6: threadfence flushes L2, catastrophic).
// bf16 MFMA 16x16x32, K=128 in 4 steps. Epilogue: e = exp2(EXP_SCALE*s);
// row partials via 16-lane shfl -> 1 atomic per row; col partials via
// cross-wave LDS reduce -> 128 coalesced atomics per block.
// LDS rows padded 128->136 (row stride 272 B -> only free 2-way
// conflicts; 16B alignment preserved for b128 access).
// ---------------------------------------------------------------------------
__global__ __launch_bounds__(256) void gemm_exp_kernel(
    const bf16_t* __restrict__ zi, const bf16_t* __restrict__ zj,
    float* __restrict__ rowDenom, float* __restrict__ colDenom)
{
    __shared__ __align__(16) bf16_t zi_s[128][136];
    __shared__ __align__(16) bf16_t zj_s[128][136];
    __shared__ float colRed[4][128];

    const int tid = threadIdx.x;
    const int ti = blockIdx.x, tj = blockIdx.y;

    // Stage 128x128 bf16 of each matrix: 2048 16B-chunks / matrix, 8 iters.
#pragma unroll
    for (int it = 0; it < 8; ++it) {
        int c = it * 256 + tid;
        int row = c >> 4;          // 16 chunks per row
        int col = (c & 15) << 3;   // 8 bf16 per chunk
        *(uint4*)&zi_s[row][col] =
            *(const uint4*)(zi + ((size_t)(ti * 128 + row)) * DIM + col);
        *(uint4*)&zj_s[row][col] =
            *(const uint4*)(zj + ((size_t)(tj * 128 + row)) * DIM + col);
    }
    __syncthreads();

    const int wave = tid >> 6;
    const int lane = tid & 63;
    const int l15  = lane & 15;
    const int quad = lane >> 4;

    const f32x4 vzero = {0.f, 0.f, 0.f, 0.f};
    f32x4 acc[2][8];
#pragma unroll
    for (int rt = 0; rt < 2; ++rt)
#pragma unroll
        for (int ct = 0; ct < 8; ++ct) acc[rt][ct] = vzero;

#pragma unroll
    for (int ks = 0; ks < 4; ++ks) {
        int k0 = ks * 32 + quad * 8;
        bf16x8 afrag[2], bfrag[8];
#pragma unroll
        for (int rt = 0; rt < 2; ++rt)
            afrag[rt] = *(const bf16x8*)&zi_s[(wave * 2 + rt) * 16 + l15][k0];
#pragma unroll
        for (int ct = 0; ct < 8; ++ct)
            bfrag[ct] = *(const bf16x8*)&zj_s[ct * 16 + l15][k0];
#pragma unroll
        for (int rt = 0; rt < 2; ++rt)
#pragma unroll
            for (int ct = 0; ct < 8; ++ct)
                acc[rt][ct] = __builtin_amdgcn_mfma_f32_16x16x32_bf16(
                    afrag[rt], bfrag[ct], acc[rt][ct], 0, 0, 0);
    }

    // Epilogue: exp and partial sums.
    float rowPart[2][4] = {{0.f, 0.f, 0.f, 0.f}, {0.f, 0.f, 0.f, 0.f}};
    float colPart[8]    = {0.f, 0.f, 0.f, 0.f, 0.f, 0.f, 0.f, 0.f};
#pragma unroll
    for (int rt = 0; rt < 2; ++rt)
#pragma unroll
        for (int ct = 0; ct < 8; ++ct)
#pragma unroll
            for (int r = 0; r < 4; ++r) {
                float e = exp2f(acc[rt][ct][r] * EXP_SCALE);
                rowPart[rt][r] += e;   // row = (wave*2+rt)*16 + quad*4 + r
                colPart[ct]    += e;   // col = ct*16 + l15
            }

    // Row sums: each wave's rows see all 128 tile columns; 16-lane shfl
    // reduce completes them. One atomic per row per block.
#pragma unroll
    for (int rt = 0; rt < 2; ++rt)
#pragma unroll
        for (int r = 0; r < 4; ++r) {
            float v = rowPart[rt][r];
            v += __shfl_xor(v, 1);
            v += __shfl_xor(v, 2);
            v += __shfl_xor(v, 4);
            v += __shfl_xor(v, 8);
            if (l15 == 0) {
                int grow = ti * 128 + (wave * 2 + rt) * 16 + quad * 4 + r;
                atomicAdd(&rowDenom[grow], v);
            }
        }

    // Col sums: quad shfl-reduce, then cross-wave LDS reduce, then one
    // coalesced atomic per column per block.
#pragma unroll
    for (int ct = 0; ct < 8; ++ct) {
        float v = colPart[ct];
        v += __shfl_xor(v, 16);
        v += __shfl_xor(v, 32);
        if (quad == 0) colRed[wave][ct * 16 + l15] = v;
    }
    __syncthreads();
    if (tid < 128) {
        float s = colRed[0][tid] + colRed[1][tid] + colRed[2][tid] + colRed[3][tid];
        atomicAdd(&colDenom[tj * 128 + tid], s);
    }
}

// ---------------------------------------------------------------------------
// Kernel C (REWRITTEN): old version was 1 block x 256 threads with
// acc += logf(load)+logf(load)-8*load in a 16-deep serial loop -- a
// latency chain of ~48 scattered cold loads on ONE CU (~15 us by the
// round-6/round-4 time algebra). New: 1 block x 1024 threads (16 waves);
// each thread issues exactly 3 independent float4 loads up front (one
// latency epoch), 8 logf, wave shfl-reduce, 16-way LDS reduce.
// ---------------------------------------------------------------------------
__global__ __launch_bounds__(1024) void finalize_kernel(
    const float* __restrict__ denoms, const float* __restrict__ pos,
    float* __restrict__ out)
{
    const float4* rowD4 = (const float4*)denoms;            // 1024 float4
    const float4* colD4 = (const float4*)(denoms + BATCH);  // 1024 float4
    const float4* pos4  = (const float4*)pos;               // 1024 float4

    const int tid  = threadIdx.x;
    const int lane = tid & 63;
    const int wv   = tid >> 6;

    float4 rd = rowD4[tid];
    float4 cd = colD4[tid];
    float4 p  = pos4[tid];

    float acc = logf(rd.x) + logf(rd.y) + logf(rd.z) + logf(rd.w)
              + logf(cd.x) + logf(cd.y) + logf(cd.z) + logf(cd.w)
              - 8.0f * (p.x + p.y + p.z + p.w);

#pragma unroll
    for (int m = 1; m < 64; m <<= 1) acc += __shfl_xor(acc, m);

    __shared__ float red[16];
    if (lane == 0) red[wv] = acc;
    __syncthreads();
    if (wv == 0) {
        float v = (lane < 16) ? red[lane] : 0.0f;
#pragma unroll
        for (int m = 1; m < 64; m <<= 1) v += __shfl_xor(v, m);
        if (lane == 0) out[0] = v * (1.0f / (2.0f * BATCH));
    }
}

extern "C" void kernel_launch(void* const* d_in, const int* in_sizes, int n_in,
                              void* d_out, int out_size, void* d_ws, size_t ws_size,
                              hipStream_t stream) {
    const float* emb_i = (const float*)d_in[0];
    const float* emb_j = (const float*)d_in[1];
    float* out = (float*)d_out;

    char* ws = (char*)d_ws;
    bf16_t* zi     = (bf16_t*)(ws);                 // 1 MB
    bf16_t* zj     = (bf16_t*)(ws + (1u << 20));    // 1 MB
    float*  denoms = (float*)(ws + (2u << 20));     // 32 KB (row ++ col)
    float*  pos    = denoms + 2 * BATCH;            // 16 KB

    normalize_kernel<<<BATCH / 4, 256, 0, stream>>>(emb_i, emb_j, zi, zj, pos, denoms);
    gemm_exp_kernel<<<dim3(NT, NT), 256, 0, stream>>>(zi, zj, denoms, denoms + BATCH);
    finalize_kernel<<<1, 1024, 0, stream>>>(denoms, pos, out);
}